// Round 3
// baseline (79.422 us; speedup 1.0000x reference)
//
#include <hip/hip_runtime.h>
#include <math.h>

#define B_   4
#define N_   512
#define DIN  256
#define E_   64
#define H_   4
#define QT_  8      // q rows per attn block

// ---------------------------------------------------------------------------
// Projection kernel: per block computes Y[32 rows][64 cols] = X_tile * W + b
// grid = B*H*3*(N/32) = 768 blocks, 256 threads (3 blocks/CU, 12 waves/CU).
// p=0 -> Q [B][H][N][E] (+qn2), p=1 -> KT [B][H][E][N] (+kn2), p=2 -> V.
// K-loop in 2 chunks of 128 with register prefetch of chunk 1.
// ---------------------------------------------------------------------------
__global__ __launch_bounds__(256) void proj_kernel(
    const float* __restrict__ x,
    const float* __restrict__ Wq, const float* __restrict__ bq,
    const float* __restrict__ Wk, const float* __restrict__ bk,
    const float* __restrict__ Wv, const float* __restrict__ bv,
    float* __restrict__ Q, float* __restrict__ KT, float* __restrict__ V,
    float* __restrict__ qn2, float* __restrict__ kn2)
{
    const int tid = threadIdx.x;
    int blk = blockIdx.x;
    const int tile = blk & 15;  blk >>= 4;
    const int p    = blk % 3;   blk /= 3;
    const int h    = blk & 3;
    const int b    = blk >> 2;

    const float* W;
    const float* bias;
    if (p == 0)      { W = Wq; bias = bq; }
    else if (p == 1) { W = Wk; bias = bk; }
    else             { W = Wv; bias = bv; }
    W    += (size_t)h * DIN * E_;
    bias += h * E_;

    const int rowbase = tile * 32;
    const float* xb = x + ((size_t)b * N_ + rowbase) * DIN;

    __shared__ float XsT[128][34];   // [d][r] transposed, pad->conflict-free
    __shared__ float Ws[128][64];    // [d][c] linear (reads are row-broadcast)

    const int tr = tid >> 4;   // 0..15 -> rows tr*2, tr*2+1
    const int tc = tid & 15;   // 0..15 -> cols tc*4..tc*4+3

    // ---- load chunk 0 (dc=0) to regs ----
    float  xr[16];
    float4 wr[8];
    {
        const float4* Wg4 = (const float4*)(W);
        #pragma unroll
        for (int i = 0; i < 16; ++i) {
            int l = tid + i * 256;           // 4096 elems: 32 rows x 128 d
            xr[i] = xb[(l >> 7) * DIN + (l & 127)];
        }
        #pragma unroll
        for (int i = 0; i < 8; ++i) wr[i] = Wg4[tid + i * 256];
    }
    // write chunk 0 to LDS
    #pragma unroll
    for (int i = 0; i < 16; ++i) {
        int l = tid + i * 256;
        XsT[l & 127][l >> 7] = xr[i];
    }
    #pragma unroll
    for (int i = 0; i < 8; ++i) ((float4*)Ws)[tid + i * 256] = wr[i];
    __syncthreads();

    // ---- prefetch chunk 1 (dc=128) ----
    {
        const float4* Wg4 = (const float4*)(W + 128 * E_);
        #pragma unroll
        for (int i = 0; i < 16; ++i) {
            int l = tid + i * 256;
            xr[i] = xb[(l >> 7) * DIN + 128 + (l & 127)];
        }
        #pragma unroll
        for (int i = 0; i < 8; ++i) wr[i] = Wg4[tid + i * 256];
    }

    float acc[2][4];
    #pragma unroll
    for (int i = 0; i < 2; ++i)
        #pragma unroll
        for (int j = 0; j < 4; ++j) acc[i][j] = 0.f;

    // ---- compute chunk 0 ----
    #pragma unroll 8
    for (int d = 0; d < 128; ++d) {
        float2 xv = *(const float2*)&XsT[d][tr * 2];
        float4 wv = *(const float4*)&Ws[d][tc * 4];
        acc[0][0] = fmaf(xv.x, wv.x, acc[0][0]);
        acc[0][1] = fmaf(xv.x, wv.y, acc[0][1]);
        acc[0][2] = fmaf(xv.x, wv.z, acc[0][2]);
        acc[0][3] = fmaf(xv.x, wv.w, acc[0][3]);
        acc[1][0] = fmaf(xv.y, wv.x, acc[1][0]);
        acc[1][1] = fmaf(xv.y, wv.y, acc[1][1]);
        acc[1][2] = fmaf(xv.y, wv.z, acc[1][2]);
        acc[1][3] = fmaf(xv.y, wv.w, acc[1][3]);
    }
    __syncthreads();

    // write chunk 1, compute
    #pragma unroll
    for (int i = 0; i < 16; ++i) {
        int l = tid + i * 256;
        XsT[l & 127][l >> 7] = xr[i];
    }
    #pragma unroll
    for (int i = 0; i < 8; ++i) ((float4*)Ws)[tid + i * 256] = wr[i];
    __syncthreads();

    #pragma unroll 8
    for (int d = 0; d < 128; ++d) {
        float2 xv = *(const float2*)&XsT[d][tr * 2];
        float4 wv = *(const float4*)&Ws[d][tc * 4];
        acc[0][0] = fmaf(xv.x, wv.x, acc[0][0]);
        acc[0][1] = fmaf(xv.x, wv.y, acc[0][1]);
        acc[0][2] = fmaf(xv.x, wv.z, acc[0][2]);
        acc[0][3] = fmaf(xv.x, wv.w, acc[0][3]);
        acc[1][0] = fmaf(xv.y, wv.x, acc[1][0]);
        acc[1][1] = fmaf(xv.y, wv.y, acc[1][1]);
        acc[1][2] = fmaf(xv.y, wv.z, acc[1][2]);
        acc[1][3] = fmaf(xv.y, wv.w, acc[1][3]);
    }

    // ---- epilogue: bias, norms, stores ----
    const size_t bh = (size_t)b * H_ + h;
    float4 bias4 = *(const float4*)&bias[tc * 4];
    float v0[4], v1[4];
    v0[0] = acc[0][0] + bias4.x; v0[1] = acc[0][1] + bias4.y;
    v0[2] = acc[0][2] + bias4.z; v0[3] = acc[0][3] + bias4.w;
    v1[0] = acc[1][0] + bias4.x; v1[1] = acc[1][1] + bias4.y;
    v1[2] = acc[1][2] + bias4.z; v1[3] = acc[1][3] + bias4.w;

    if (p < 2) {   // row squared-norms for q (p=0) and k (p=1)
        float s0 = 0.f, s1 = 0.f;
        #pragma unroll
        for (int j = 0; j < 4; ++j) {
            s0 = fmaf(v0[j], v0[j], s0);
            s1 = fmaf(v1[j], v1[j], s1);
        }
        #pragma unroll
        for (int off = 1; off < 16; off <<= 1) {
            s0 += __shfl_xor(s0, off, 64);
            s1 += __shfl_xor(s1, off, 64);
        }
        if (tc == 0) {
            float* nrm = (p == 0) ? qn2 : kn2;
            int row = rowbase + tr * 2;
            nrm[bh * N_ + row]     = s0;
            nrm[bh * N_ + row + 1] = s1;
        }
    }

    if (p == 1) {
        // K transposed: KT[b][h][e][n]
        float* o = KT + bh * (size_t)(E_ * N_);
        int r0 = rowbase + tr * 2;
        #pragma unroll
        for (int j = 0; j < 4; ++j) {
            o[(size_t)(tc * 4 + j) * N_ + r0]     = v0[j];
            o[(size_t)(tc * 4 + j) * N_ + r0 + 1] = v1[j];
        }
    } else {
        float* o = (p == 0 ? Q : V) + bh * (size_t)(N_ * E_);
        int r0 = rowbase + tr * 2;
        *(float4*)&o[(size_t)r0 * E_ + tc * 4]       = make_float4(v0[0], v0[1], v0[2], v0[3]);
        *(float4*)&o[(size_t)(r0 + 1) * E_ + tc * 4] = make_float4(v1[0], v1[1], v1[2], v1[3]);
    }
}

// ---------------------------------------------------------------------------
// Attention kernel: 512 threads/block, one (b, h, 8-row q tile) per block.
// grid = 1024 blocks -> 4 blocks/CU x 8 waves = 32 waves/CU (100% occupancy
// target, VGPR forced <= 64 by launch_bounds).
// Phase 1: logits (1 key column per thread, 8 rows).
// Phase 2: softmax, 1 row per wave.
// Phase 3: PV split over m-quarters, float4 V, LDS partial reduce.
// ---------------------------------------------------------------------------
template <int HEAD>
__device__ __forceinline__ void compute_logits(
    const float* __restrict__ KTbh, const float (*qv_s)[8],
    float (*P)[512], const float* __restrict__ kn2bh, const float* qn2s,
    int tid)
{
    float acc[QT_];
    #pragma unroll
    for (int r = 0; r < QT_; ++r) acc[r] = 0.f;

    float kn2v = 0.f;
    if (HEAD == 1 || HEAD == 3) kn2v = kn2bh[tid];   // issue early

    const float* kp = KTbh + tid;
    #pragma unroll 8
    for (int e = 0; e < 64; ++e) {
        float kv = kp[e * N_];
        float4 qa = *(const float4*)&qv_s[e][0];
        float4 qb = *(const float4*)&qv_s[e][4];
        float qv[QT_] = {qa.x, qa.y, qa.z, qa.w, qb.x, qb.y, qb.z, qb.w};
        #pragma unroll
        for (int r = 0; r < QT_; ++r) {
            if (HEAD == 2) {
                acc[r] += fabsf(kv - qv[r]);          // L1
            } else {
                acc[r] = fmaf(qv[r], kv, acc[r]);     // dot (sdp/cos/L2-dot)
            }
        }
    }

    float rsq_k = (HEAD == 1) ? rsqrtf(kn2v) : 0.f;
    #pragma unroll
    for (int r = 0; r < QT_; ++r) {
        float l;
        if (HEAD == 0)      l = acc[r] * 0.125f;
        else if (HEAD == 1) l = acc[r] * rsqrtf(qn2s[r]) * rsq_k;
        else if (HEAD == 2) l = -acc[r];
        else                l = -sqrtf(fmaxf(qn2s[r] + kn2v - 2.f * acc[r], 0.f));
        P[r][tid] = l;
    }
}

__global__ __launch_bounds__(512, 8) void attn_kernel(
    const float* __restrict__ Q, const float* __restrict__ KT,
    const float* __restrict__ V, const float* __restrict__ qn2,
    const float* __restrict__ kn2, float* __restrict__ out)
{
    const int tid = threadIdx.x;
    int blk = blockIdx.x;
    const int qt = blk & 63;
    const int h  = (blk >> 6) & 3;
    const int b  = blk >> 8;

    const size_t bh = (size_t)b * H_ + h;
    const float* Qbh  = Q  + bh * (size_t)(N_ * E_) + (size_t)qt * QT_ * E_;
    const float* KTbh = KT + bh * (size_t)(E_ * N_);
    const float* Vbh  = V  + bh * (size_t)(N_ * E_);

    __shared__ float qv_s[64][8];     // [e][r]; reads are wave-uniform b128
    __shared__ float P[QT_][512];
    __shared__ float part[4][520];    // PV partials, +8 pad -> spread banks
    __shared__ float qn2s[QT_];
    __shared__ float rinv[QT_];

    // stage q (coalesced) + row norms
    {
        int r = tid >> 6, e = tid & 63;
        qv_s[e][r] = Qbh[tid];
    }
    if (tid < QT_) qn2s[tid] = qn2[bh * N_ + qt * QT_ + tid];
    __syncthreads();

    if (h == 0)      compute_logits<0>(KTbh, qv_s, P, kn2 + bh * N_, qn2s, tid);
    else if (h == 1) compute_logits<1>(KTbh, qv_s, P, kn2 + bh * N_, qn2s, tid);
    else if (h == 2) compute_logits<2>(KTbh, qv_s, P, kn2 + bh * N_, qn2s, tid);
    else             compute_logits<3>(KTbh, qv_s, P, kn2 + bh * N_, qn2s, tid);
    __syncthreads();

    // softmax: wave w owns row w
    {
        const int wv = tid >> 6, lane = tid & 63;
        float vals[8];
        float mx = -1e30f;
        #pragma unroll
        for (int k = 0; k < 8; ++k) {
            vals[k] = P[wv][lane + k * 64];
            mx = fmaxf(mx, vals[k]);
        }
        #pragma unroll
        for (int off = 32; off; off >>= 1) mx = fmaxf(mx, __shfl_xor(mx, off, 64));
        float s = 0.f;
        #pragma unroll
        for (int k = 0; k < 8; ++k) {
            float pv = __expf(vals[k] - mx);
            s += pv;
            P[wv][lane + k * 64] = pv;
        }
        #pragma unroll
        for (int off = 32; off; off >>= 1) s += __shfl_xor(s, off, 64);
        if (lane == 0) rinv[wv] = 1.f / s;
    }
    __syncthreads();

    // PV: thread = (ms, r, e4): m-quarter x row x e-quad. 16 FMA / 5 loads.
    {
        const int ms = tid >> 7;
        const int r  = (tid >> 4) & 7;
        const int e4 = tid & 15;
        float4 a = make_float4(0.f, 0.f, 0.f, 0.f);

        const float* vb = Vbh + e4 * 4;
        #pragma unroll 4
        for (int m = ms * 128; m < ms * 128 + 128; m += 4) {
            float4 p  = *(const float4*)&P[r][m];
            float4 w0 = *(const float4*)&vb[(size_t)(m + 0) * E_];
            float4 w1 = *(const float4*)&vb[(size_t)(m + 1) * E_];
            float4 w2 = *(const float4*)&vb[(size_t)(m + 2) * E_];
            float4 w3 = *(const float4*)&vb[(size_t)(m + 3) * E_];
            a.x = fmaf(p.x, w0.x, a.x); a.y = fmaf(p.x, w0.y, a.y);
            a.z = fmaf(p.x, w0.z, a.z); a.w = fmaf(p.x, w0.w, a.w);
            a.x = fmaf(p.y, w1.x, a.x); a.y = fmaf(p.y, w1.y, a.y);
            a.z = fmaf(p.y, w1.z, a.z); a.w = fmaf(p.y, w1.w, a.w);
            a.x = fmaf(p.z, w2.x, a.x); a.y = fmaf(p.z, w2.y, a.y);
            a.z = fmaf(p.z, w2.z, a.z); a.w = fmaf(p.z, w2.w, a.w);
            a.x = fmaf(p.w, w3.x, a.x); a.y = fmaf(p.w, w3.y, a.y);
            a.z = fmaf(p.w, w3.z, a.z); a.w = fmaf(p.w, w3.w, a.w);
        }
        *(float4*)&part[ms][r * 64 + e4 * 4] = a;
    }
    __syncthreads();

    // reduce partials over ms, scale, store
    {
        const int rr = tid >> 6, e = tid & 63;
        float s = part[0][rr * 64 + e] + part[1][rr * 64 + e]
                + part[2][rr * 64 + e] + part[3][rr * 64 + e];
        int n = qt * QT_ + rr;
        out[((size_t)b * N_ + n) * (H_ * E_) + h * E_ + e] = s * rinv[rr];
    }
}

// ---------------------------------------------------------------------------
extern "C" void kernel_launch(void* const* d_in, const int* in_sizes, int n_in,
                              void* d_out, int out_size, void* d_ws, size_t ws_size,
                              hipStream_t stream)
{
    const float* x  = (const float*)d_in[0];
    const float* Wq = (const float*)d_in[1];
    const float* bq = (const float*)d_in[2];
    const float* Wk = (const float*)d_in[3];
    const float* bk = (const float*)d_in[4];
    const float* Wv = (const float*)d_in[5];
    const float* bv = (const float*)d_in[6];
    float* out = (float*)d_out;

    float* ws = (float*)d_ws;
    const size_t qkv = (size_t)B_ * H_ * N_ * E_;  // 524288 floats
    float* Q   = ws;
    float* KT  = ws + qkv;
    float* V   = ws + 2 * qkv;
    float* qn2 = ws + 3 * qkv;                     // B*H*N = 8192 floats
    float* kn2 = qn2 + (size_t)B_ * H_ * N_;

    proj_kernel<<<B_ * H_ * 3 * (N_ / 32), 256, 0, stream>>>(
        x, Wq, bq, Wk, bk, Wv, bv, Q, KT, V, qn2, kn2);
    attn_kernel<<<B_ * H_ * (N_ / QT_), 512, 0, stream>>>(Q, KT, V, qn2, kn2, out);
}

// Round 5
// 64.271 us; speedup vs baseline: 1.2357x; 1.2357x over previous
//
#include <hip/hip_runtime.h>
#include <math.h>

#define B_   4
#define N_   512
#define DIN  256
#define E_   64
#define H_   4
#define QT_  4      // q rows per attn block

// ---------------------------------------------------------------------------
// Projection kernel: per block computes Y[32 rows][64 cols] = X_tile * W + b
// grid = B*H*3*(N/32) = 768 blocks, 256 threads.
// p=0 -> Q [B][H][N][E] (+qn2), p=1 -> KT [B][H][E][N] (+kn2), p=2 -> V.
// KT is transposed through LDS so global writes are full-line coalesced.
// ---------------------------------------------------------------------------
__global__ __launch_bounds__(256) void proj_kernel(
    const float* __restrict__ x,
    const float* __restrict__ Wq, const float* __restrict__ bq,
    const float* __restrict__ Wk, const float* __restrict__ bk,
    const float* __restrict__ Wv, const float* __restrict__ bv,
    float* __restrict__ Q, float* __restrict__ KT, float* __restrict__ V,
    float* __restrict__ qn2, float* __restrict__ kn2)
{
    const int tid = threadIdx.x;
    int blk = blockIdx.x;
    const int tile = blk & 15;  blk >>= 4;
    const int p    = blk % 3;   blk /= 3;
    const int h    = blk & 3;
    const int b    = blk >> 2;

    const float* W;
    const float* bias;
    if (p == 0)      { W = Wq; bias = bq; }
    else if (p == 1) { W = Wk; bias = bk; }
    else             { W = Wv; bias = bv; }
    W    += (size_t)h * DIN * E_;
    bias += h * E_;

    const int rowbase = tile * 32;
    const float* xb = x + ((size_t)b * N_ + rowbase) * DIN;

    __shared__ float XsT[64][34];   // [d][r] transposed; float2-aligned pad
    __shared__ float Ws[64][64];    // [d][c]; reads are 16 distinct b128 -> ok
    __shared__ float Ys[64][33];    // KT transpose staging (scalar reads)

    const int tr = tid >> 4;   // 0..15 -> rows tr*2, tr*2+1
    const int tc = tid & 15;   // 0..15 -> cols tc*4..tc*4+3

    float acc[2][4];
    #pragma unroll
    for (int i = 0; i < 2; ++i)
        #pragma unroll
        for (int j = 0; j < 4; ++j) acc[i][j] = 0.f;

    for (int dc = 0; dc < DIN; dc += 64) {
        for (int l = tid; l < 2048; l += 256) {     // 32 rows x 64 d
            int r = l >> 6, d = l & 63;
            XsT[d][r] = xb[r * DIN + dc + d];
        }
        {   // 64 d x 64 cols as float4
            const float4* Wg4 = (const float4*)(W + (size_t)dc * E_);
            #pragma unroll
            for (int i = 0; i < 4; ++i) ((float4*)Ws)[tid + i * 256] = Wg4[tid + i * 256];
        }
        __syncthreads();

        #pragma unroll 8
        for (int d = 0; d < 64; ++d) {
            float2 xv = *(const float2*)&XsT[d][tr * 2];
            float4 wv = *(const float4*)&Ws[d][tc * 4];
            acc[0][0] = fmaf(xv.x, wv.x, acc[0][0]);
            acc[0][1] = fmaf(xv.x, wv.y, acc[0][1]);
            acc[0][2] = fmaf(xv.x, wv.z, acc[0][2]);
            acc[0][3] = fmaf(xv.x, wv.w, acc[0][3]);
            acc[1][0] = fmaf(xv.y, wv.x, acc[1][0]);
            acc[1][1] = fmaf(xv.y, wv.y, acc[1][1]);
            acc[1][2] = fmaf(xv.y, wv.z, acc[1][2]);
            acc[1][3] = fmaf(xv.y, wv.w, acc[1][3]);
        }
        __syncthreads();
    }

    // ---- epilogue: bias, norms, stores ----
    const size_t bh = (size_t)b * H_ + h;
    float4 bias4 = *(const float4*)&bias[tc * 4];
    float v0[4], v1[4];
    v0[0] = acc[0][0] + bias4.x; v0[1] = acc[0][1] + bias4.y;
    v0[2] = acc[0][2] + bias4.z; v0[3] = acc[0][3] + bias4.w;
    v1[0] = acc[1][0] + bias4.x; v1[1] = acc[1][1] + bias4.y;
    v1[2] = acc[1][2] + bias4.z; v1[3] = acc[1][3] + bias4.w;

    if (p < 2) {   // row squared-norms for q (p=0) and k (p=1)
        float s0 = 0.f, s1 = 0.f;
        #pragma unroll
        for (int j = 0; j < 4; ++j) {
            s0 = fmaf(v0[j], v0[j], s0);
            s1 = fmaf(v1[j], v1[j], s1);
        }
        #pragma unroll
        for (int off = 1; off < 16; off <<= 1) {
            s0 += __shfl_xor(s0, off, 64);
            s1 += __shfl_xor(s1, off, 64);
        }
        if (tc == 0) {
            float* nrm = (p == 0) ? qn2 : kn2;
            int row = rowbase + tr * 2;
            nrm[bh * N_ + row]     = s0;
            nrm[bh * N_ + row + 1] = s1;
        }
    }

    if (p == 1) {
        // stage Y into LDS as [e][n], then write KT[b][h][e][n] coalesced
        #pragma unroll
        for (int j = 0; j < 4; ++j) {
            Ys[tc * 4 + j][tr * 2]     = v0[j];
            Ys[tc * 4 + j][tr * 2 + 1] = v1[j];
        }
        __syncthreads();
        const int e  = tid >> 2;         // 0..63
        const int n0 = (tid & 3) * 8;    // 0,8,16,24
        float4 a, c;
        a.x = Ys[e][n0 + 0]; a.y = Ys[e][n0 + 1];
        a.z = Ys[e][n0 + 2]; a.w = Ys[e][n0 + 3];
        c.x = Ys[e][n0 + 4]; c.y = Ys[e][n0 + 5];
        c.z = Ys[e][n0 + 6]; c.w = Ys[e][n0 + 7];
        float* o = KT + bh * (size_t)(E_ * N_) + (size_t)e * N_ + rowbase + n0;
        *(float4*)&o[0] = a;
        *(float4*)&o[4] = c;
    } else {
        float* o = (p == 0 ? Q : V) + bh * (size_t)(N_ * E_);
        int r0 = rowbase + tr * 2;
        *(float4*)&o[(size_t)r0 * E_ + tc * 4]       = make_float4(v0[0], v0[1], v0[2], v0[3]);
        *(float4*)&o[(size_t)(r0 + 1) * E_ + tc * 4] = make_float4(v1[0], v1[1], v1[2], v1[3]);
    }
}

// ---------------------------------------------------------------------------
// Attention kernel: 256 threads, one (b, h, 4-row q tile) per block.
// grid = B*H*(N/4) = 2048 blocks -> 8 blocks/CU x 4 waves = 32 waves/CU.
// Phase 1: logits, 2 key columns per thread, 4 rows.
// Phase 2: softmax, 1 row per wave.
// Phase 3: PV over m-halves (8 FMA / 6 loads), small LDS reduce.
// ---------------------------------------------------------------------------
template <int HEAD>
__device__ __forceinline__ void compute_logits(
    const float* __restrict__ KTbh, const float (*qv_s)[4],
    float (*P)[512], const float* __restrict__ kn2bh, const float* qn2s,
    int tid)
{
    float acc0[QT_], acc1[QT_];
    #pragma unroll
    for (int r = 0; r < QT_; ++r) { acc0[r] = 0.f; acc1[r] = 0.f; }

    const int m0 = tid;
    const int m1 = tid + 256;

    float kn2v0 = 0.f, kn2v1 = 0.f;
    if (HEAD == 1 || HEAD == 3) { kn2v0 = kn2bh[m0]; kn2v1 = kn2bh[m1]; }

    const float* kp = KTbh + m0;
    #pragma unroll 8
    for (int e = 0; e < 64; ++e) {
        float k0 = kp[e * N_];
        float k1 = kp[e * N_ + 256];
        float4 qa = *(const float4*)&qv_s[e][0];
        float qv[QT_] = {qa.x, qa.y, qa.z, qa.w};
        #pragma unroll
        for (int r = 0; r < QT_; ++r) {
            if (HEAD == 2) {                          // L1
                acc0[r] += fabsf(k0 - qv[r]);
                acc1[r] += fabsf(k1 - qv[r]);
            } else {                                  // dot (sdp/cos/L2-dot)
                acc0[r] = fmaf(qv[r], k0, acc0[r]);
                acc1[r] = fmaf(qv[r], k1, acc1[r]);
            }
        }
    }

    float rk0 = (HEAD == 1) ? rsqrtf(kn2v0) : 0.f;
    float rk1 = (HEAD == 1) ? rsqrtf(kn2v1) : 0.f;
    #pragma unroll
    for (int r = 0; r < QT_; ++r) {
        float l0, l1;
        if (HEAD == 0)      { l0 = acc0[r] * 0.125f; l1 = acc1[r] * 0.125f; }
        else if (HEAD == 1) { float rq = rsqrtf(qn2s[r]);
                              l0 = acc0[r] * rq * rk0; l1 = acc1[r] * rq * rk1; }
        else if (HEAD == 2) { l0 = -acc0[r]; l1 = -acc1[r]; }
        else                { l0 = -sqrtf(fmaxf(qn2s[r] + kn2v0 - 2.f * acc0[r], 0.f));
                              l1 = -sqrtf(fmaxf(qn2s[r] + kn2v1 - 2.f * acc1[r], 0.f)); }
        P[r][m0] = l0;
        P[r][m1] = l1;
    }
}

__global__ __launch_bounds__(256, 8) void attn_kernel(
    const float* __restrict__ Q, const float* __restrict__ KT,
    const float* __restrict__ V, const float* __restrict__ qn2,
    const float* __restrict__ kn2, float* __restrict__ out)
{
    const int tid = threadIdx.x;
    int blk = blockIdx.x;
    const int qt = blk & 127;
    const int h  = (blk >> 7) & 3;
    const int b  = blk >> 9;

    const size_t bh = (size_t)b * H_ + h;
    const float* Qbh  = Q  + bh * (size_t)(N_ * E_) + (size_t)qt * QT_ * E_;
    const float* KTbh = KT + bh * (size_t)(E_ * N_);
    const float* Vbh  = V  + bh * (size_t)(N_ * E_);

    __shared__ float qv_s[64][4];     // [e][r]; reads wave-uniform b128
    __shared__ float P[QT_][512];
    __shared__ float part[2][QT_][64];
    __shared__ float qn2s[QT_];
    __shared__ float rinv[QT_];

    // stage q (coalesced) + q row norms
    {
        int r = tid >> 6, e = tid & 63;
        qv_s[e][r] = Qbh[tid];
    }
    if (tid < QT_) qn2s[tid] = qn2[bh * N_ + qt * QT_ + tid];
    __syncthreads();

    if (h == 0)      compute_logits<0>(KTbh, qv_s, P, kn2 + bh * N_, qn2s, tid);
    else if (h == 1) compute_logits<1>(KTbh, qv_s, P, kn2 + bh * N_, qn2s, tid);
    else if (h == 2) compute_logits<2>(KTbh, qv_s, P, kn2 + bh * N_, qn2s, tid);
    else             compute_logits<3>(KTbh, qv_s, P, kn2 + bh * N_, qn2s, tid);
    __syncthreads();

    // softmax: wave w owns row w
    {
        const int wv = tid >> 6, lane = tid & 63;
        float vals[8];
        float mx = -1e30f;
        #pragma unroll
        for (int k = 0; k < 8; ++k) {
            vals[k] = P[wv][lane + k * 64];
            mx = fmaxf(mx, vals[k]);
        }
        #pragma unroll
        for (int off = 32; off; off >>= 1) mx = fmaxf(mx, __shfl_xor(mx, off, 64));
        float s = 0.f;
        #pragma unroll
        for (int k = 0; k < 8; ++k) {
            float pv = __expf(vals[k] - mx);
            s += pv;
            P[wv][lane + k * 64] = pv;
        }
        #pragma unroll
        for (int off = 32; off; off >>= 1) s += __shfl_xor(s, off, 64);
        if (lane == 0) rinv[wv] = 1.f / s;
    }
    __syncthreads();

    // PV: thread = (m-half, row-pair, e). 8 FMA / 6 loads, partials in LDS.
    {
        const int mh = tid >> 7;          // 0..1
        const int rp = (tid >> 6) & 1;    // rows rp*2, rp*2+1
        const int e  = tid & 63;
        const int r0 = rp * 2, r1 = r0 + 1;
        float a0 = 0.f, a1 = 0.f;

        const float* vb = Vbh + e;
        #pragma unroll 4
        for (int m = mh * 256; m < mh * 256 + 256; m += 4) {
            float w0 = vb[(size_t)(m + 0) * E_];
            float w1 = vb[(size_t)(m + 1) * E_];
            float w2 = vb[(size_t)(m + 2) * E_];
            float w3 = vb[(size_t)(m + 3) * E_];
            float4 p0 = *(const float4*)&P[r0][m];
            float4 p1 = *(const float4*)&P[r1][m];
            a0 = fmaf(p0.x, w0, a0); a0 = fmaf(p0.y, w1, a0);
            a0 = fmaf(p0.z, w2, a0); a0 = fmaf(p0.w, w3, a0);
            a1 = fmaf(p1.x, w0, a1); a1 = fmaf(p1.y, w1, a1);
            a1 = fmaf(p1.z, w2, a1); a1 = fmaf(p1.w, w3, a1);
        }
        part[mh][r0][e] = a0;
        part[mh][r1][e] = a1;
    }
    __syncthreads();

    // reduce partials, scale, store
    {
        const int r = tid >> 6, e = tid & 63;
        float s = part[0][r][e] + part[1][r][e];
        int n = qt * QT_ + r;
        out[((size_t)b * N_ + n) * (H_ * E_) + h * E_ + e] = s * rinv[r];
    }
}

// ---------------------------------------------------------------------------
extern "C" void kernel_launch(void* const* d_in, const int* in_sizes, int n_in,
                              void* d_out, int out_size, void* d_ws, size_t ws_size,
                              hipStream_t stream)
{
    const float* x  = (const float*)d_in[0];
    const float* Wq = (const float*)d_in[1];
    const float* bq = (const float*)d_in[2];
    const float* Wk = (const float*)d_in[3];
    const float* bk = (const float*)d_in[4];
    const float* Wv = (const float*)d_in[5];
    const float* bv = (const float*)d_in[6];
    float* out = (float*)d_out;

    float* ws = (float*)d_ws;
    const size_t qkv = (size_t)B_ * H_ * N_ * E_;  // 524288 floats
    float* Q   = ws;
    float* KT  = ws + qkv;
    float* V   = ws + 2 * qkv;
    float* qn2 = ws + 3 * qkv;                     // B*H*N = 8192 floats
    float* kn2 = qn2 + (size_t)B_ * H_ * N_;

    proj_kernel<<<B_ * H_ * 3 * (N_ / 32), 256, 0, stream>>>(
        x, Wq, bq, Wk, bk, Wv, bv, Q, KT, V, qn2, kn2);
    attn_kernel<<<B_ * H_ * (N_ / QT_), 256, 0, stream>>>(Q, KT, V, qn2, kn2, out);
}

// Round 6
// 58.970 us; speedup vs baseline: 1.3468x; 1.0899x over previous
//
#include <hip/hip_runtime.h>
#include <hip/hip_bf16.h>
#include <math.h>

#define B_   4
#define N_   512
#define DIN  256
#define E_   64
#define H_   4

typedef __attribute__((ext_vector_type(8))) short bf16x8;
typedef __attribute__((ext_vector_type(4))) float f32x4;

__device__ __forceinline__ unsigned short f2bf(float f) {
    __hip_bfloat16 h = __float2bfloat16(f);
    return *reinterpret_cast<unsigned short*>(&h);
}

// ---------------------------------------------------------------------------
// Projection: per block Y[32 rows][64 cols] = X_tile * W + b.  grid=768.
// Outputs: p=0: Q f32 [bh][512][64] + Qp bf16 (+qn2)
//          p=1: KT f32 [bh][64][512] (LDS transpose) + Kp bf16 row-major (+kn2)
//          p=2: VTp bf16 [bh][64][512] (LDS transpose)
// ---------------------------------------------------------------------------
__global__ __launch_bounds__(256) void proj_kernel(
    const float* __restrict__ x,
    const float* __restrict__ Wq, const float* __restrict__ bq,
    const float* __restrict__ Wk, const float* __restrict__ bk,
    const float* __restrict__ Wv, const float* __restrict__ bv,
    float* __restrict__ Q, float* __restrict__ KT,
    float* __restrict__ qn2, float* __restrict__ kn2,
    unsigned short* __restrict__ Qp, unsigned short* __restrict__ Kp,
    unsigned short* __restrict__ VTp)
{
    const int tid = threadIdx.x;
    int blk = blockIdx.x;
    const int tile = blk & 15;  blk >>= 4;
    const int p    = blk % 3;   blk /= 3;
    const int h    = blk & 3;
    const int b    = blk >> 2;

    const float* W;
    const float* bias;
    if (p == 0)      { W = Wq; bias = bq; }
    else if (p == 1) { W = Wk; bias = bk; }
    else             { W = Wv; bias = bv; }
    W    += (size_t)h * DIN * E_;
    bias += h * E_;

    const int rowbase = tile * 32;
    const float* xb = x + ((size_t)b * N_ + rowbase) * DIN;

    __shared__ float XsT[64][34];
    __shared__ float Ws[64][64];
    __shared__ float Ys[64][33];    // transpose staging for KT / VT

    const int tr = tid >> 4;
    const int tc = tid & 15;

    float acc[2][4];
    #pragma unroll
    for (int i = 0; i < 2; ++i)
        #pragma unroll
        for (int j = 0; j < 4; ++j) acc[i][j] = 0.f;

    for (int dc = 0; dc < DIN; dc += 64) {
        for (int l = tid; l < 2048; l += 256) {
            int r = l >> 6, d = l & 63;
            XsT[d][r] = xb[r * DIN + dc + d];
        }
        {
            const float4* Wg4 = (const float4*)(W + (size_t)dc * E_);
            #pragma unroll
            for (int i = 0; i < 4; ++i) ((float4*)Ws)[tid + i * 256] = Wg4[tid + i * 256];
        }
        __syncthreads();

        #pragma unroll 8
        for (int d = 0; d < 64; ++d) {
            float2 xv = *(const float2*)&XsT[d][tr * 2];
            float4 wv = *(const float4*)&Ws[d][tc * 4];
            acc[0][0] = fmaf(xv.x, wv.x, acc[0][0]);
            acc[0][1] = fmaf(xv.x, wv.y, acc[0][1]);
            acc[0][2] = fmaf(xv.x, wv.z, acc[0][2]);
            acc[0][3] = fmaf(xv.x, wv.w, acc[0][3]);
            acc[1][0] = fmaf(xv.y, wv.x, acc[1][0]);
            acc[1][1] = fmaf(xv.y, wv.y, acc[1][1]);
            acc[1][2] = fmaf(xv.y, wv.z, acc[1][2]);
            acc[1][3] = fmaf(xv.y, wv.w, acc[1][3]);
        }
        __syncthreads();
    }

    const size_t bh = (size_t)b * H_ + h;
    float4 bias4 = *(const float4*)&bias[tc * 4];
    float v0[4], v1[4];
    v0[0] = acc[0][0] + bias4.x; v0[1] = acc[0][1] + bias4.y;
    v0[2] = acc[0][2] + bias4.z; v0[3] = acc[0][3] + bias4.w;
    v1[0] = acc[1][0] + bias4.x; v1[1] = acc[1][1] + bias4.y;
    v1[2] = acc[1][2] + bias4.z; v1[3] = acc[1][3] + bias4.w;

    const int r0 = rowbase + tr * 2;

    if (p < 2) {   // row squared-norms for q (p=0) and k (p=1)
        float s0 = 0.f, s1 = 0.f;
        #pragma unroll
        for (int j = 0; j < 4; ++j) {
            s0 = fmaf(v0[j], v0[j], s0);
            s1 = fmaf(v1[j], v1[j], s1);
        }
        #pragma unroll
        for (int off = 1; off < 16; off <<= 1) {
            s0 += __shfl_xor(s0, off, 64);
            s1 += __shfl_xor(s1, off, 64);
        }
        if (tc == 0) {
            float* nrm = (p == 0) ? qn2 : kn2;
            nrm[bh * N_ + r0]     = s0;
            nrm[bh * N_ + r0 + 1] = s1;
        }
        // bf16 row-major packs (Qp / Kp)
        unsigned short* pk = ((p == 0) ? Qp : Kp) + bh * (size_t)(N_ * E_);
        ushort4 u0, u1;
        u0.x = f2bf(v0[0]); u0.y = f2bf(v0[1]); u0.z = f2bf(v0[2]); u0.w = f2bf(v0[3]);
        u1.x = f2bf(v1[0]); u1.y = f2bf(v1[1]); u1.z = f2bf(v1[2]); u1.w = f2bf(v1[3]);
        *(ushort4*)&pk[(size_t)r0 * E_ + tc * 4]       = u0;
        *(ushort4*)&pk[(size_t)(r0 + 1) * E_ + tc * 4] = u1;
    }

    if (p == 0) {
        float* o = Q + bh * (size_t)(N_ * E_);
        *(float4*)&o[(size_t)r0 * E_ + tc * 4]       = make_float4(v0[0], v0[1], v0[2], v0[3]);
        *(float4*)&o[(size_t)(r0 + 1) * E_ + tc * 4] = make_float4(v1[0], v1[1], v1[2], v1[3]);
    } else {
        // transpose via LDS: Ys[e][n-local]
        #pragma unroll
        for (int j = 0; j < 4; ++j) {
            Ys[tc * 4 + j][tr * 2]     = v0[j];
            Ys[tc * 4 + j][tr * 2 + 1] = v1[j];
        }
        __syncthreads();
        const int e  = tid >> 2;
        const int n0 = (tid & 3) * 8;
        if (p == 1) {  // KT f32 (for the L1 head)
            float* o = KT + bh * (size_t)(E_ * N_) + (size_t)e * N_ + rowbase + n0;
            float4 a, c;
            a.x = Ys[e][n0 + 0]; a.y = Ys[e][n0 + 1];
            a.z = Ys[e][n0 + 2]; a.w = Ys[e][n0 + 3];
            c.x = Ys[e][n0 + 4]; c.y = Ys[e][n0 + 5];
            c.z = Ys[e][n0 + 6]; c.w = Ys[e][n0 + 7];
            *(float4*)&o[0] = a;
            *(float4*)&o[4] = c;
        } else {       // VT bf16 (PV B-fragments)
            unsigned short* o = VTp + bh * (size_t)(E_ * N_) + (size_t)e * N_ + rowbase + n0;
            ushort4 a, c;
            a.x = f2bf(Ys[e][n0 + 0]); a.y = f2bf(Ys[e][n0 + 1]);
            a.z = f2bf(Ys[e][n0 + 2]); a.w = f2bf(Ys[e][n0 + 3]);
            c.x = f2bf(Ys[e][n0 + 4]); c.y = f2bf(Ys[e][n0 + 5]);
            c.z = f2bf(Ys[e][n0 + 6]); c.w = f2bf(Ys[e][n0 + 7]);
            *(ushort4*)&o[0] = a;
            *(ushort4*)&o[4] = c;
        }
    }
}

// ---------------------------------------------------------------------------
// Attention: grid = 16 bh x 32 q-tiles = 512 blocks, 256 threads (4 waves).
// Block = 16 q-rows; wave w owns keys [w*128, w*128+128).
// Heads 0/1/3: MFMA logits. Head 2 (L1): f32 VALU logits from f32 KT.
// Softmax: regs + tiny LDS cross-wave max/sum. P: bf16 in XOR-swizzled LDS
// (wave-private). PV: MFMA from P A-frags + VT B-frags; LDS partial reduce.
// ---------------------------------------------------------------------------
template <int HEAD>
__device__ __forceinline__ void mfma_logits(
    int w, int lane, size_t bh, int q0,
    const unsigned short* __restrict__ Qp,
    const unsigned short* __restrict__ Kp,
    const float* __restrict__ qn2, const float* __restrict__ kn2,
    char* Pw, float (*wmax)[16], float (*wsum)[16])
{
    const int g = lane >> 4, li = lane & 15;
    const int row0 = g * 4;
    const unsigned short* Qpb = Qp + bh * (N_ * E_) + (size_t)q0 * E_;
    const unsigned short* Kpb = Kp + bh * (N_ * E_);

    bf16x8 a0 = *(const bf16x8*)&Qpb[li * E_ + g * 8];
    bf16x8 a1 = *(const bf16x8*)&Qpb[li * E_ + g * 8 + 32];

    float qrow[4];
    if (HEAD == 1) {
        #pragma unroll
        for (int j = 0; j < 4; ++j) qrow[j] = rsqrtf(qn2[bh * N_ + q0 + row0 + j]);
    } else if (HEAD == 3) {
        #pragma unroll
        for (int j = 0; j < 4; ++j) qrow[j] = qn2[bh * N_ + q0 + row0 + j];
    }

    float lg[8][4];
    #pragma unroll
    for (int t = 0; t < 8; ++t) {
        const int m0 = w * 128 + t * 16;
        const unsigned short* kb = &Kpb[(size_t)(m0 + li) * E_ + g * 8];
        bf16x8 b0 = *(const bf16x8*)&kb[0];
        bf16x8 b1 = *(const bf16x8*)&kb[32];
        f32x4 acc = {0.f, 0.f, 0.f, 0.f};
        acc = __builtin_amdgcn_mfma_f32_16x16x32_bf16(a0, b0, acc, 0, 0, 0);
        acc = __builtin_amdgcn_mfma_f32_16x16x32_bf16(a1, b1, acc, 0, 0, 0);
        float kcol = 0.f, rk = 0.f;
        if (HEAD == 1) { kcol = kn2[bh * N_ + m0 + li]; rk = rsqrtf(kcol); }
        if (HEAD == 3) { kcol = kn2[bh * N_ + m0 + li]; }
        #pragma unroll
        for (int j = 0; j < 4; ++j) {
            float d = acc[j];
            if (HEAD == 0)      lg[t][j] = d * 0.125f;
            else if (HEAD == 1) lg[t][j] = d * qrow[j] * rk;
            else                lg[t][j] = -sqrtf(fmaxf(qrow[j] + kcol - 2.f * d, 0.f));
        }
    }

    // row max: over t in-lane, then across the 16-lane (li) group
    float mx[4], gm[4];
    #pragma unroll
    for (int j = 0; j < 4; ++j) {
        float m = lg[0][j];
        #pragma unroll
        for (int t = 1; t < 8; ++t) m = fmaxf(m, lg[t][j]);
        #pragma unroll
        for (int off = 1; off < 16; off <<= 1) m = fmaxf(m, __shfl_xor(m, off, 64));
        mx[j] = m;
    }
    if (li == 0) {
        #pragma unroll
        for (int j = 0; j < 4; ++j) wmax[w][row0 + j] = mx[j];
    }
    __syncthreads();
    #pragma unroll
    for (int j = 0; j < 4; ++j)
        gm[j] = fmaxf(fmaxf(wmax[0][row0 + j], wmax[1][row0 + j]),
                      fmaxf(wmax[2][row0 + j], wmax[3][row0 + j]));

    float sm[4] = {0.f, 0.f, 0.f, 0.f};
    #pragma unroll
    for (int t = 0; t < 8; ++t) {
        #pragma unroll
        for (int j = 0; j < 4; ++j) {
            const int row = row0 + j;
            float pv = __expf(lg[t][j] - gm[j]);
            sm[j] += pv;
            const int byte = (row * 256 + (t * 16 + li) * 2) ^ ((row & 7) << 4);
            *(unsigned short*)(Pw + byte) = f2bf(pv);
        }
    }
    #pragma unroll
    for (int j = 0; j < 4; ++j) {
        float s = sm[j];
        #pragma unroll
        for (int off = 1; off < 16; off <<= 1) s += __shfl_xor(s, off, 64);
        if (li == 0) wsum[w][row0 + j] = s;
    }
}

__global__ __launch_bounds__(256) void attn_kernel(
    const float* __restrict__ Qf, const float* __restrict__ KT,
    const unsigned short* __restrict__ Qp, const unsigned short* __restrict__ Kp,
    const unsigned short* __restrict__ VTp,
    const float* __restrict__ qn2, const float* __restrict__ kn2,
    float* __restrict__ out)
{
    const int tid  = threadIdx.x;
    const int w    = tid >> 6;
    const int lane = tid & 63;
    int blk = blockIdx.x;
    const int qt = blk & 31;
    const int h  = (blk >> 5) & 3;
    const int b  = blk >> 7;
    const size_t bh = (size_t)b * H_ + h;
    const int q0 = qt * 16;

    __shared__ unsigned short Plds[4][2048];   // per-wave [16 rows][128 keys] bf16, swizzled
    __shared__ float part[4][16][68];
    __shared__ float wmax[4][16];
    __shared__ float wsum[4][16];
    __shared__ float q_lds[16][72];

    const int g = lane >> 4, li = lane & 15;
    char* Pw = (char*)&Plds[w][0];

    if (h == 2) {
        // ---- L1 head: f32-exact VALU logits ----
        {
            const int i4 = tid * 4;
            const int r = i4 >> 6, c = i4 & 63;
            *(float4*)&q_lds[r][c] =
                *(const float4*)&Qf[bh * (N_ * E_) + (size_t)(q0 + r) * E_ + c];
        }
        __syncthreads();

        float acc0[16], acc1[16];
        #pragma unroll
        for (int r = 0; r < 16; ++r) { acc0[r] = 0.f; acc1[r] = 0.f; }

        const float* kp = KT + bh * (E_ * N_) + w * 128 + 2 * lane;
        for (int c = 0; c < 4; ++c) {
            float2 kk[16];
            #pragma unroll
            for (int i = 0; i < 16; ++i) kk[i] = *(const float2*)&kp[(c * 16 + i) * N_];
            #pragma unroll
            for (int r = 0; r < 16; ++r) {
                const float* qr = &q_lds[r][c * 16];
                float4 qa = *(const float4*)&qr[0];
                float4 qb = *(const float4*)&qr[4];
                float4 qc = *(const float4*)&qr[8];
                float4 qd = *(const float4*)&qr[12];
                float qv[16] = {qa.x, qa.y, qa.z, qa.w, qb.x, qb.y, qb.z, qb.w,
                                qc.x, qc.y, qc.z, qc.w, qd.x, qd.y, qd.z, qd.w};
                #pragma unroll
                for (int i = 0; i < 16; ++i) {
                    acc0[r] += fabsf(kk[i].x - qv[i]);
                    acc1[r] += fabsf(kk[i].y - qv[i]);
                }
            }
        }

        // softmax over -d: track min distance
        #pragma unroll
        for (int r = 0; r < 16; ++r) {
            float mn = fminf(acc0[r], acc1[r]);
            #pragma unroll
            for (int off = 1; off < 64; off <<= 1) mn = fminf(mn, __shfl_xor(mn, off, 64));
            if (lane == 0) wmax[w][r] = mn;   // min-d
        }
        __syncthreads();
        #pragma unroll
        for (int r = 0; r < 16; ++r) {
            float gmn = fminf(fminf(wmax[0][r], wmax[1][r]), fminf(wmax[2][r], wmax[3][r]));
            float p0 = __expf(gmn - acc0[r]);
            float p1 = __expf(gmn - acc1[r]);
            float s = p0 + p1;
            #pragma unroll
            for (int off = 1; off < 64; off <<= 1) s += __shfl_xor(s, off, 64);
            if (lane == 0) wsum[w][r] = s;
            unsigned int pk = (unsigned int)f2bf(p0) | ((unsigned int)f2bf(p1) << 16);
            const int byte = (r * 256 + lane * 4) ^ ((r & 7) << 4);
            *(unsigned int*)(Pw + byte) = pk;
        }
    } else if (h == 0) {
        mfma_logits<0>(w, lane, bh, q0, Qp, Kp, qn2, kn2, Pw, wmax, wsum);
    } else if (h == 1) {
        mfma_logits<1>(w, lane, bh, q0, Qp, Kp, qn2, kn2, Pw, wmax, wsum);
    } else {
        mfma_logits<3>(w, lane, bh, q0, Qp, Kp, qn2, kn2, Pw, wmax, wsum);
    }

    // ---- PV: wave-private P (no barrier needed), MFMA over 4 k-steps ----
    {
        bf16x8 pa[4];
        #pragma unroll
        for (int s = 0; s < 4; ++s) {
            const int byte = (li * 256 + (s * 32 + g * 8) * 2) ^ ((li & 7) << 4);
            pa[s] = *(const bf16x8*)(Pw + byte);
        }
        const unsigned short* Vb = VTp + bh * (E_ * N_);
        const int row0 = g * 4;
        #pragma unroll
        for (int et = 0; et < 4; ++et) {
            f32x4 acc = {0.f, 0.f, 0.f, 0.f};
            #pragma unroll
            for (int s = 0; s < 4; ++s) {
                bf16x8 vb = *(const bf16x8*)&Vb[(size_t)(et * 16 + li) * N_
                                                + w * 128 + s * 32 + g * 8];
                acc = __builtin_amdgcn_mfma_f32_16x16x32_bf16(pa[s], vb, acc, 0, 0, 0);
            }
            #pragma unroll
            for (int j = 0; j < 4; ++j) part[w][row0 + j][et * 16 + li] = acc[j];
        }
    }
    __syncthreads();

    // ---- reduce partials over waves, normalize, store ----
    #pragma unroll
    for (int k = 0; k < 4; ++k) {
        const int idx = tid + k * 256;
        const int row = idx >> 6, e = idx & 63;
        float s = part[0][row][e] + part[1][row][e] + part[2][row][e] + part[3][row][e];
        float rs = wsum[0][row] + wsum[1][row] + wsum[2][row] + wsum[3][row];
        out[((size_t)b * N_ + q0 + row) * (H_ * E_) + h * E_ + e] = s / rs;
    }
}

// ---------------------------------------------------------------------------
extern "C" void kernel_launch(void* const* d_in, const int* in_sizes, int n_in,
                              void* d_out, int out_size, void* d_ws, size_t ws_size,
                              hipStream_t stream)
{
    const float* x  = (const float*)d_in[0];
    const float* Wq = (const float*)d_in[1];
    const float* bq = (const float*)d_in[2];
    const float* Wk = (const float*)d_in[3];
    const float* bk = (const float*)d_in[4];
    const float* Wv = (const float*)d_in[5];
    const float* bv = (const float*)d_in[6];
    float* out = (float*)d_out;

    const size_t qkv = (size_t)B_ * H_ * N_ * E_;   // 524288
    float* Q   = (float*)d_ws;
    float* KT  = Q + qkv;
    float* qn2 = KT + qkv;
    float* kn2 = qn2 + (size_t)B_ * H_ * N_;
    unsigned short* Qp  = (unsigned short*)(kn2 + (size_t)B_ * H_ * N_);
    unsigned short* Kp  = Qp + qkv;
    unsigned short* VTp = Kp + qkv;

    proj_kernel<<<B_ * H_ * 3 * (N_ / 32), 256, 0, stream>>>(
        x, Wq, bq, Wk, bk, Wv, bv, Q, KT, qn2, kn2, Qp, Kp, VTp);
    attn_kernel<<<B_ * H_ * (N_ / 16), 256, 0, stream>>>(
        Q, KT, Qp, Kp, VTp, qn2, kn2, out);
}